// Round 11
// baseline (106.940 us; speedup 1.0000x reference)
//
#include <hip/hip_runtime.h>
#include <hip/hip_bf16.h>

typedef __bf16 bf16_t;
typedef __bf16 bf16x8 __attribute__((ext_vector_type(8)));
typedef float f32x4 __attribute__((ext_vector_type(4)));
typedef float f32x8 __attribute__((ext_vector_type(8)));
typedef float f32x16 __attribute__((ext_vector_type(16)));
typedef unsigned int u32;

#define GAS __attribute__((address_space(1)))
#define LAS __attribute__((address_space(3)))

#define B_N 32
#define T_N 2048
#define C_N 256
#define F_N 1024
#define NSPLIT 16
#define TSUB 128
#define NCHUNK 32
#define CHB 33792               // 16KB W1 + 1KB bias-kg-pair + 16KB W2
#define NITER 16                // 2 chunks per barrier interval

#define MF(A, B, C) __builtin_amdgcn_mfma_f32_32x32x16_bf16((A), (B), (C), 0, 0, 0)

// ---------------- weight prep: per-chunk images {W1 | bias-K-ext | W2} ----------------
// W1: entry (kg 0..31, hl 0..31) 16B = { bf16(W1[kg*8+j][ch*32+hl]) } at kg*512 + hl*16
// bias K-ext: kg-pair at 16384: g=0 entry hl -> {bf16(b1[ch*32+hl]),0..}; g=1 -> zeros
// W2: entry (G 0..3, cc 0..255) at 17408 + G*4096 + cc*16, elem e = bf16(W2[ch*32+perm(G,e)][cc]),
//     perm = (e&3) + 8*(2*(G>>1)+(e>>2)) + 4*(G&1)   (matches swapped-GEMM1 D-reg order)
__global__ __launch_bounds__(256) void k_prep(
    const float* __restrict__ W1, const float* __restrict__ b1,
    const float* __restrict__ W2, bf16_t* __restrict__ wsW) {
  const int id = blockIdx.x * 256 + threadIdx.x;      // 0 .. 67583
  const int ch = id / 2112;
  const int r = id % 2112;
  char* base = (char*)wsW + (size_t)ch * CHB;
  if (r < 1024) {
    const int kg = r >> 5, hl = r & 31;
    const int h = (ch << 5) + hl;
    const float* src = W1 + (size_t)(kg << 3) * F_N + h;
    bf16x8 v;
#pragma unroll
    for (int j = 0; j < 8; ++j) v[j] = (bf16_t)src[(size_t)j * F_N];
    *(bf16x8*)(base + (kg << 9) + (hl << 4)) = v;
  } else if (r < 1088) {
    const int gg = (r - 1024) >> 5, hl = (r - 1024) & 31;
    bf16x8 v;
#pragma unroll
    for (int e = 0; e < 8; ++e) v[e] = (bf16_t)0.f;
    if (gg == 0) v[0] = (bf16_t)b1[(ch << 5) + hl];
    *(bf16x8*)(base + 16384 + (gg << 9) + (hl << 4)) = v;
  } else {
    const int idx = r - 1088;
    const int G = idx >> 8, cc = idx & 255;
    bf16x8 v;
#pragma unroll
    for (int e = 0; e < 8; ++e) {
      const int hid = (ch << 5) + (e & 3) + ((((G >> 1) << 1) + (e >> 2)) << 3) + ((G & 1) << 2);
      v[e] = (bf16_t)W2[(size_t)hid * C_N + cc];
    }
    *(bf16x8*)(base + 17408 + (G << 12) + (cc << 4)) = v;
  }
}

// ---------------- stats pass 1: partial sum / sumsq over a T-slice ----------------
__global__ __launch_bounds__(256) void k_stats_partial(
    const float* __restrict__ x, float* __restrict__ psum, float* __restrict__ psq) {
  const int blk = blockIdx.x;
  const int b = blk / NSPLIT, s = blk % NSPLIT;
  const int tid = threadIdx.x;
  const int c4 = (tid & 63) << 2;
  const int tg = tid >> 6;
  const float* xb = x + ((size_t)b * T_N + (size_t)s * TSUB) * C_N;
  f32x4 sum = {0.f, 0.f, 0.f, 0.f};
  f32x4 sq  = {0.f, 0.f, 0.f, 0.f};
#pragma unroll 4
  for (int i = 0; i < TSUB / 4; ++i) {
    const int t = tg + (i << 2);
    f32x4 v = *(const f32x4*)(xb + (size_t)t * C_N + c4);
    sum += v;
    sq += v * v;
  }
  __shared__ f32x4 ls[256];
  __shared__ f32x4 lq[256];
  ls[tid] = sum; lq[tid] = sq;
  __syncthreads();
  if (tid < 64) {
    f32x4 S = ls[tid] + ls[tid + 64] + ls[tid + 128] + ls[tid + 192];
    f32x4 Q = lq[tid] + lq[tid + 64] + lq[tid + 128] + lq[tid + 192];
    *(f32x4*)(psum + (size_t)blk * C_N + c4) = S;
    *(f32x4*)(psq  + (size_t)blk * C_N + c4) = Q;
  }
}

// ---------------- stats pass 2: fused scale/shift (ddof=1) ----------------
__global__ __launch_bounds__(256) void k_stats_final(
    const float* __restrict__ psum, const float* __restrict__ psq,
    const float* __restrict__ gamma, const float* __restrict__ beta,
    float* __restrict__ As, float* __restrict__ Bs) {
  const int b = blockIdx.x, c = threadIdx.x;
  float S = 0.f, Q = 0.f;
#pragma unroll
  for (int s = 0; s < NSPLIT; ++s) {
    S += psum[(size_t)(b * NSPLIT + s) * C_N + c];
    Q += psq[(size_t)(b * NSPLIT + s) * C_N + c];
  }
  const float mu = S / (float)T_N;
  const float var = (Q - (float)T_N * mu * mu) / (float)(T_N - 1);
  const float a = rsqrtf(var + 1e-5f) * gamma[c];
  As[b * C_N + c] = a;
  Bs[b * C_N + c] = beta[c] - mu * a;
}

// GEMM1 (swapped, bias folded as 17th MFMA): 4-slot software-pipelined ds reads.
// D-reg r holds hid = (r&3)+8*(r>>2)+4g for token col l31. AF = relu(D1), bf16.
#define GEMM1(CB, AF) { \
  const unsigned char* wb_ = (CB) + (g << 9) + (l31 << 4); \
  bf16x8 p0 = *(const bf16x8*)((CB) + 16384 + (g << 9) + (l31 << 4)); \
  bf16x8 p1 = *(const bf16x8*)(wb_); \
  bf16x8 p2 = *(const bf16x8*)(wb_ + 1024); \
  bf16x8 p3 = *(const bf16x8*)(wb_ + 2048); \
  f32x16 D1; \
  _Pragma("unroll") for (int e_ = 0; e_ < 16; ++e_) D1[e_] = 0.f; \
  D1 = MF(p0, hext, D1);      p0 = *(const bf16x8*)(wb_ + 3072); \
  D1 = MF(p1, hfrag[0], D1);  p1 = *(const bf16x8*)(wb_ + 4096); \
  D1 = MF(p2, hfrag[1], D1);  p2 = *(const bf16x8*)(wb_ + 5120); \
  D1 = MF(p3, hfrag[2], D1);  p3 = *(const bf16x8*)(wb_ + 6144); \
  D1 = MF(p0, hfrag[3], D1);  p0 = *(const bf16x8*)(wb_ + 7168); \
  D1 = MF(p1, hfrag[4], D1);  p1 = *(const bf16x8*)(wb_ + 8192); \
  D1 = MF(p2, hfrag[5], D1);  p2 = *(const bf16x8*)(wb_ + 9216); \
  D1 = MF(p3, hfrag[6], D1);  p3 = *(const bf16x8*)(wb_ + 10240); \
  D1 = MF(p0, hfrag[7], D1);  p0 = *(const bf16x8*)(wb_ + 11264); \
  D1 = MF(p1, hfrag[8], D1);  p1 = *(const bf16x8*)(wb_ + 12288); \
  D1 = MF(p2, hfrag[9], D1);  p2 = *(const bf16x8*)(wb_ + 13312); \
  D1 = MF(p3, hfrag[10], D1); p3 = *(const bf16x8*)(wb_ + 14336); \
  D1 = MF(p0, hfrag[11], D1); p0 = *(const bf16x8*)(wb_ + 15360); \
  D1 = MF(p1, hfrag[12], D1); \
  D1 = MF(p2, hfrag[13], D1); \
  D1 = MF(p3, hfrag[14], D1); \
  D1 = MF(p0, hfrag[15], D1); \
  _Pragma("unroll") for (int r_ = 0; r_ < 16; ++r_) { \
    float v_ = D1[r_]; \
    v_ = v_ > 0.f ? v_ : 0.f; \
    AF[r_ >> 3][r_ & 7] = (bf16_t)v_; \
  } \
}

// GEMM2: 8 independent acc chains, 4-slot pipelined reads (16 frags).
#define GEMM2(CB, AF) { \
  const unsigned char* w2_ = (CB) + 17408 + (g << 12) + (l31 << 4); \
  bf16x8 q0 = *(const bf16x8*)(w2_); \
  bf16x8 q1 = *(const bf16x8*)(w2_ + 512); \
  bf16x8 q2 = *(const bf16x8*)(w2_ + 1024); \
  bf16x8 q3 = *(const bf16x8*)(w2_ + 1536); \
  accO[0] = MF(AF[0], q0, accO[0]); q0 = *(const bf16x8*)(w2_ + 2048); \
  accO[1] = MF(AF[0], q1, accO[1]); q1 = *(const bf16x8*)(w2_ + 2560); \
  accO[2] = MF(AF[0], q2, accO[2]); q2 = *(const bf16x8*)(w2_ + 3072); \
  accO[3] = MF(AF[0], q3, accO[3]); q3 = *(const bf16x8*)(w2_ + 3584); \
  accO[4] = MF(AF[0], q0, accO[4]); q0 = *(const bf16x8*)(w2_ + 8192); \
  accO[5] = MF(AF[0], q1, accO[5]); q1 = *(const bf16x8*)(w2_ + 8704); \
  accO[6] = MF(AF[0], q2, accO[6]); q2 = *(const bf16x8*)(w2_ + 9216); \
  accO[7] = MF(AF[0], q3, accO[7]); q3 = *(const bf16x8*)(w2_ + 9728); \
  accO[0] = MF(AF[1], q0, accO[0]); q0 = *(const bf16x8*)(w2_ + 10240); \
  accO[1] = MF(AF[1], q1, accO[1]); q1 = *(const bf16x8*)(w2_ + 10752); \
  accO[2] = MF(AF[1], q2, accO[2]); q2 = *(const bf16x8*)(w2_ + 11264); \
  accO[3] = MF(AF[1], q3, accO[3]); q3 = *(const bf16x8*)(w2_ + 11776); \
  accO[4] = MF(AF[1], q0, accO[4]); \
  accO[5] = MF(AF[1], q1, accO[5]); \
  accO[6] = MF(AF[1], q2, accO[6]); \
  accO[7] = MF(AF[1], q3, accO[7]); \
}

// stage one chunk-pair (67584 B) with 512 threads: 8 full 16B rounds + 2KB tail
#define STAGE(GSRC, LDST) { \
  _Pragma("unroll") for (int j_ = 0; j_ < 8; ++j_) { \
    const int off_ = (j_ << 13) + (tid << 4); \
    __builtin_amdgcn_global_load_lds((const GAS u32*)((GSRC) + off_), \
                                     (LAS u32*)((LDST) + off_), 16, 0, 0); \
  } \
  if (tid < 128) { \
    const int off_ = 65536 + (tid << 4); \
    __builtin_amdgcn_global_load_lds((const GAS u32*)((GSRC) + off_), \
                                     (LAS u32*)((LDST) + off_), 16, 0, 0); \
  } \
}

// ---------------- fused FFN: M=32/wave @ (512,2) proven envelope.
// NEW: wave-staggered chunk order within each staged pair (even waves c0->c1,
// odd waves c1->c0) so GEMM1 (MFMA-heavy) and GEMM2 (LDS-heavy) phases overlap
// across waves; setprio(1) on the GEMM1 serial chain. Register-neutral vs r10. ----------------
__global__ __launch_bounds__(512, 2) void k_ffn(
    const float* __restrict__ x, const float* __restrict__ As,
    const float* __restrict__ Bs, const float* __restrict__ b2,
    const bf16_t* __restrict__ wsW, float* __restrict__ out) {
  __shared__ __attribute__((aligned(128))) unsigned char lds[2 * 2 * CHB];  // 132KB

  const int tid = threadIdx.x;            // 0..511, 8 waves
  const int lane = tid & 63;
  const int w = tid >> 6;
  const int l31 = lane & 31;
  const int g = lane >> 5;

  const int tok0 = blockIdx.x << 8;       // 256 tokens / block
  const int b = blockIdx.x >> 3;          // 8 blocks per batch row
  const int t0 = tok0 + (w << 5);         // this wave's 32 tokens

  const char* wsb = (const char*)wsW;

  // stage pair 0 into buffer 0
  STAGE(wsb, &lds[0]);

  // constant B-frag for the bias K-extension: B[tok][kext]=1 at kext=0 (g=0 lanes)
  bf16x8 hext;
#pragma unroll
  for (int e = 0; e < 8; ++e) hext[e] = (bf16_t)0.f;
  if (g == 0) hext[0] = (bf16_t)1.0f;

  // per-wave chunk order offsets within a staged pair (stagger: w&1 swaps)
  const int offA = (w & 1) ? CHB : 0;
  const int offB = (w & 1) ? 0 : CHB;

  // prologue: normalized h fragments (64 VGPR)
  bf16x8 hfrag[16];
  {
    const float* ar = As + b * C_N;
    const float* br = Bs + b * C_N;
    const float* xrow = x + (size_t)(t0 + l31) * C_N;
#pragma unroll
    for (int ks = 0; ks < 16; ++ks) {
      const int c0 = (ks << 4) + (g << 3);
      f32x8 xv = *(const f32x8*)(xrow + c0);
      f32x8 av = *(const f32x8*)(ar + c0);
      f32x8 bv = *(const f32x8*)(br + c0);
      f32x8 hv = xv * av + bv;
#pragma unroll
      for (int e = 0; e < 8; ++e) hfrag[ks][e] = (bf16_t)hv[e];
    }
  }

  f32x16 accO[8];
#pragma unroll
  for (int nb = 0; nb < 8; ++nb)
#pragma unroll
    for (int e = 0; e < 16; ++e) accO[nb][e] = 0.f;

  __syncthreads();   // pair 0 staged

#pragma unroll 1
  for (int it = 0; it < NITER; ++it) {
    const unsigned char* buf = &lds[(it & 1) * (2 * CHB)];

    // stage next pair into the other buffer; lands well before next barrier
    if (it + 1 < NITER) {
      const char* gsrc = wsb + (size_t)(it + 1) * (2 * CHB);
      unsigned char* ldst = &lds[((it + 1) & 1) * (2 * CHB)];
      STAGE(gsrc, ldst);
    }

    const unsigned char* cA = buf + offA;   // my first chunk of the pair
    const unsigned char* cB = buf + offB;   // my second chunk

    bf16x8 afA[2], afB[2];
    __builtin_amdgcn_s_setprio(1);
    GEMM1(cA, afA);
    __builtin_amdgcn_s_setprio(0);
    GEMM2(cA, afA);
    __builtin_amdgcn_s_setprio(1);
    GEMM1(cB, afB);
    __builtin_amdgcn_s_setprio(0);
    GEMM2(cB, afB);

    if (it + 1 < NITER) __syncthreads();
  }

  // epilogue: out = accO + b2 + x   (token = t0 + 4g + rr + 8q, col = nb*32 + l31)
  {
    const float* xbase = x + (size_t)(t0 + (g << 2)) * C_N;
    float* obase = out + (size_t)(t0 + (g << 2)) * C_N;
#pragma unroll
    for (int nb = 0; nb < 8; ++nb) {
      const int c = (nb << 5) + l31;
      const float b2v = b2[c];
#pragma unroll
      for (int q = 0; q < 4; ++q) {
#pragma unroll
        for (int rr = 0; rr < 4; ++rr) {
          const size_t idx = (size_t)((q << 3) + rr) * C_N + c;
          obase[idx] = accO[nb][(q << 2) + rr] + b2v + xbase[idx];
        }
      }
    }
  }
}

extern "C" void kernel_launch(void* const* d_in, const int* in_sizes, int n_in,
                              void* d_out, int out_size, void* d_ws, size_t ws_size,
                              hipStream_t stream) {
  const float* x     = (const float*)d_in[0];
  const float* gamma = (const float*)d_in[1];
  const float* beta  = (const float*)d_in[2];
  const float* W1    = (const float*)d_in[3];
  const float* b1    = (const float*)d_in[4];
  const float* W2    = (const float*)d_in[5];
  const float* b2    = (const float*)d_in[6];
  float* out = (float*)d_out;

  char* ws = (char*)d_ws;
  bf16_t* wsW  = (bf16_t*)ws;                           // 32 x 33792 = 1.03 MB
  float* psum  = (float*)(ws + (1088 << 10));           // 512 KB
  float* psq   = (float*)(ws + (1600 << 10));           // 512 KB
  float* As    = (float*)(ws + (2112 << 10));           // 32 KB
  float* Bs    = (float*)(ws + (2112 << 10) + (32 << 10));

  k_prep<<<264, 256, 0, stream>>>(W1, b1, W2, wsW);
  k_stats_partial<<<B_N * NSPLIT, 256, 0, stream>>>(x, psum, psq);
  k_stats_final<<<B_N, 256, 0, stream>>>(psum, psq, gamma, beta, As, Bs);
  k_ffn<<<256, 512, 0, stream>>>(x, As, Bs, b2, wsW, out);
}

// Round 12
// 99.916 us; speedup vs baseline: 1.0703x; 1.0703x over previous
//
#include <hip/hip_runtime.h>
#include <hip/hip_bf16.h>

typedef __bf16 bf16_t;
typedef __bf16 bf16x8 __attribute__((ext_vector_type(8)));
typedef float f32x4 __attribute__((ext_vector_type(4)));
typedef float f32x8 __attribute__((ext_vector_type(8)));
typedef unsigned int u32;

#define GAS __attribute__((address_space(1)))
#define LAS __attribute__((address_space(3)))

#define B_N 32
#define T_N 2048
#define C_N 256
#define F_N 1024
#define NSPLIT 16
#define TSUB 128
#define NCHUNK 32
#define CHB 32896               // 16KB W1 + 16KB W2 + 128B bias
#define PAIRB (2 * CHB)         // 65792
#define NITER 16                // 2 chunks per barrier interval

#define MF16(A, B, C) __builtin_amdgcn_mfma_f32_16x16x32_bf16((A), (B), (C), 0, 0, 0)

// ---------------- weight prep: per-chunk images {W1 | W2 | bias} ----------------
// 16x16x32 fragment layouts (HW-verified, round-1 kernel): A/B k=(l>>4)*8+e,
// C/D row=(l>>4)*4+r col=l&15.
// W1 entry (ks 0..7, ht 0..1, G 0..3, c 0..15) 16B at ks*2048+ht*1024+G*256+c*16:
//   { bf16(W1[ks*32+8G+e][ch*32+ht*16+c]) e=0..7 }
// W2 entry (ct 0..15, G, c) 16B at 16384+ct*1024+G*256+c*16:
//   { bf16(W2[ch*32 + 4G+(e&3)+16*(e>>2)][ct*16+c]) }   (perm matches D1 reg order)
// bias (ht, G) f32x4 at 32768+ht*64+G*16 = b1[ch*32+ht*16+4G .. +3]
__global__ __launch_bounds__(256) void k_prep(
    const float* __restrict__ W1, const float* __restrict__ b1,
    const float* __restrict__ W2, bf16_t* __restrict__ wsW) {
  const int id = blockIdx.x * 256 + threadIdx.x;      // 0 .. 65791
  const int ch = id / 2056;
  const int r = id % 2056;
  char* base = (char*)wsW + (size_t)ch * CHB;
  if (r < 1024) {
    const int ks = r >> 7, rem = r & 127;
    const int ht = rem >> 6, rem2 = rem & 63;
    const int G = rem2 >> 4, c = rem2 & 15;
    const int h = (ch << 5) + (ht << 4) + c;
    bf16x8 v;
#pragma unroll
    for (int e = 0; e < 8; ++e)
      v[e] = (bf16_t)W1[(size_t)((ks << 5) + (G << 3) + e) * F_N + h];
    *(bf16x8*)(base + (ks << 11) + (ht << 10) + (G << 8) + (c << 4)) = v;
  } else if (r < 2048) {
    const int t = r - 1024;
    const int ct = t >> 6, rem = t & 63;
    const int G = rem >> 4, c = rem & 15;
    bf16x8 v;
#pragma unroll
    for (int e = 0; e < 8; ++e) {
      const int hid = (ch << 5) + (G << 2) + (e & 3) + ((e >> 2) << 4);
      v[e] = (bf16_t)W2[(size_t)hid * C_N + (ct << 4) + c];
    }
    *(bf16x8*)(base + 16384 + (ct << 10) + (G << 8) + (c << 4)) = v;
  } else {
    const int t = r - 2048;       // 0..7
    const int ht = t >> 2, G = t & 3;
    f32x4 v;
#pragma unroll
    for (int j = 0; j < 4; ++j)
      v[j] = b1[(ch << 5) + (ht << 4) + (G << 2) + j];
    *(f32x4*)(base + 32768 + (ht << 6) + (G << 4)) = v;
  }
}

// ---------------- stats pass 1: partial sum / sumsq over a T-slice ----------------
__global__ __launch_bounds__(256) void k_stats_partial(
    const float* __restrict__ x, float* __restrict__ psum, float* __restrict__ psq) {
  const int blk = blockIdx.x;
  const int b = blk / NSPLIT, s = blk % NSPLIT;
  const int tid = threadIdx.x;
  const int c4 = (tid & 63) << 2;
  const int tg = tid >> 6;
  const float* xb = x + ((size_t)b * T_N + (size_t)s * TSUB) * C_N;
  f32x4 sum = {0.f, 0.f, 0.f, 0.f};
  f32x4 sq  = {0.f, 0.f, 0.f, 0.f};
#pragma unroll 4
  for (int i = 0; i < TSUB / 4; ++i) {
    const int t = tg + (i << 2);
    f32x4 v = *(const f32x4*)(xb + (size_t)t * C_N + c4);
    sum += v;
    sq += v * v;
  }
  __shared__ f32x4 ls[256];
  __shared__ f32x4 lq[256];
  ls[tid] = sum; lq[tid] = sq;
  __syncthreads();
  if (tid < 64) {
    f32x4 S = ls[tid] + ls[tid + 64] + ls[tid + 128] + ls[tid + 192];
    f32x4 Q = lq[tid] + lq[tid + 64] + lq[tid + 128] + lq[tid + 192];
    *(f32x4*)(psum + (size_t)blk * C_N + c4) = S;
    *(f32x4*)(psq  + (size_t)blk * C_N + c4) = Q;
  }
}

// ---------------- stats pass 2: fused scale/shift (ddof=1) ----------------
__global__ __launch_bounds__(256) void k_stats_final(
    const float* __restrict__ psum, const float* __restrict__ psq,
    const float* __restrict__ gamma, const float* __restrict__ beta,
    float* __restrict__ As, float* __restrict__ Bs) {
  const int b = blockIdx.x, c = threadIdx.x;
  float S = 0.f, Q = 0.f;
#pragma unroll
  for (int s = 0; s < NSPLIT; ++s) {
    S += psum[(size_t)(b * NSPLIT + s) * C_N + c];
    Q += psq[(size_t)(b * NSPLIT + s) * C_N + c];
  }
  const float mu = S / (float)T_N;
  const float var = (Q - (float)T_N * mu * mu) / (float)(T_N - 1);
  const float a = rsqrtf(var + 1e-5f) * gamma[c];
  As[b * C_N + c] = a;
  Bs[b * C_N + c] = beta[c] - mu * a;
}

// one full chunk: GEMM1 (4 chains of 8) -> bias+ReLU pack -> GEMM2 (32 indep)
#define R1(off) (*(const bf16x8*)(w1_ + (off)))
#define R2(off) (*(const bf16x8*)(w2_ + (off)))
#define CHUNK(CB) { \
  const unsigned char* w1_ = (CB) + lane16; \
  const unsigned char* w2_ = (CB) + 16384 + lane16; \
  bf16x8 p0 = R1(0), p1 = R1(1024), p2 = R1(2048), p3 = R1(3072); \
  f32x4 D00 = Z4, D01 = Z4, D10 = Z4, D11 = Z4; \
  D00 = MF16(p0, hfrag[0][0], D00); D01 = MF16(p0, hfrag[1][0], D01); p0 = R1(4096); \
  D10 = MF16(p1, hfrag[0][0], D10); D11 = MF16(p1, hfrag[1][0], D11); p1 = R1(5120); \
  D00 = MF16(p2, hfrag[0][1], D00); D01 = MF16(p2, hfrag[1][1], D01); p2 = R1(6144); \
  D10 = MF16(p3, hfrag[0][1], D10); D11 = MF16(p3, hfrag[1][1], D11); p3 = R1(7168); \
  D00 = MF16(p0, hfrag[0][2], D00); D01 = MF16(p0, hfrag[1][2], D01); p0 = R1(8192); \
  D10 = MF16(p1, hfrag[0][2], D10); D11 = MF16(p1, hfrag[1][2], D11); p1 = R1(9216); \
  D00 = MF16(p2, hfrag[0][3], D00); D01 = MF16(p2, hfrag[1][3], D01); p2 = R1(10240); \
  D10 = MF16(p3, hfrag[0][3], D10); D11 = MF16(p3, hfrag[1][3], D11); p3 = R1(11264); \
  D00 = MF16(p0, hfrag[0][4], D00); D01 = MF16(p0, hfrag[1][4], D01); p0 = R1(12288); \
  D10 = MF16(p1, hfrag[0][4], D10); D11 = MF16(p1, hfrag[1][4], D11); p1 = R1(13312); \
  D00 = MF16(p2, hfrag[0][5], D00); D01 = MF16(p2, hfrag[1][5], D01); p2 = R1(14336); \
  D10 = MF16(p3, hfrag[0][5], D10); D11 = MF16(p3, hfrag[1][5], D11); p3 = R1(15360); \
  D00 = MF16(p0, hfrag[0][6], D00); D01 = MF16(p0, hfrag[1][6], D01); \
  D10 = MF16(p1, hfrag[0][6], D10); D11 = MF16(p1, hfrag[1][6], D11); \
  D00 = MF16(p2, hfrag[0][7], D00); D01 = MF16(p2, hfrag[1][7], D01); \
  D10 = MF16(p3, hfrag[0][7], D10); D11 = MF16(p3, hfrag[1][7], D11); \
  const f32x4 bq0 = *(const f32x4*)((CB) + 32768 + (G4 << 4)); \
  const f32x4 bq1 = *(const f32x4*)((CB) + 32768 + 64 + (G4 << 4)); \
  bf16x8 af0, af1; \
  _Pragma("unroll") for (int e_ = 0; e_ < 8; ++e_) { \
    const int r_ = e_ & 3; \
    const float bb = (e_ < 4 ? bq0 : bq1)[r_]; \
    float v0 = (e_ < 4 ? D00[r_] : D10[r_]) + bb; \
    float v1 = (e_ < 4 ? D01[r_] : D11[r_]) + bb; \
    v0 = v0 > 0.f ? v0 : 0.f; \
    v1 = v1 > 0.f ? v1 : 0.f; \
    af0[e_] = (bf16_t)v0; af1[e_] = (bf16_t)v1; \
  } \
  bf16x8 q0 = R2(0), q1 = R2(1024), q2 = R2(2048), q3 = R2(3072); \
  accO[0][0]  = MF16(af0, q0, accO[0][0]);  accO[1][0]  = MF16(af1, q0, accO[1][0]);  q0 = R2(4096); \
  accO[0][1]  = MF16(af0, q1, accO[0][1]);  accO[1][1]  = MF16(af1, q1, accO[1][1]);  q1 = R2(5120); \
  accO[0][2]  = MF16(af0, q2, accO[0][2]);  accO[1][2]  = MF16(af1, q2, accO[1][2]);  q2 = R2(6144); \
  accO[0][3]  = MF16(af0, q3, accO[0][3]);  accO[1][3]  = MF16(af1, q3, accO[1][3]);  q3 = R2(7168); \
  accO[0][4]  = MF16(af0, q0, accO[0][4]);  accO[1][4]  = MF16(af1, q0, accO[1][4]);  q0 = R2(8192); \
  accO[0][5]  = MF16(af0, q1, accO[0][5]);  accO[1][5]  = MF16(af1, q1, accO[1][5]);  q1 = R2(9216); \
  accO[0][6]  = MF16(af0, q2, accO[0][6]);  accO[1][6]  = MF16(af1, q2, accO[1][6]);  q2 = R2(10240); \
  accO[0][7]  = MF16(af0, q3, accO[0][7]);  accO[1][7]  = MF16(af1, q3, accO[1][7]);  q3 = R2(11264); \
  accO[0][8]  = MF16(af0, q0, accO[0][8]);  accO[1][8]  = MF16(af1, q0, accO[1][8]);  q0 = R2(12288); \
  accO[0][9]  = MF16(af0, q1, accO[0][9]);  accO[1][9]  = MF16(af1, q1, accO[1][9]);  q1 = R2(13312); \
  accO[0][10] = MF16(af0, q2, accO[0][10]); accO[1][10] = MF16(af1, q2, accO[1][10]); q2 = R2(14336); \
  accO[0][11] = MF16(af0, q3, accO[0][11]); accO[1][11] = MF16(af1, q3, accO[1][11]); q3 = R2(15360); \
  accO[0][12] = MF16(af0, q0, accO[0][12]); accO[1][12] = MF16(af1, q0, accO[1][12]); \
  accO[0][13] = MF16(af0, q1, accO[0][13]); accO[1][13] = MF16(af1, q1, accO[1][13]); \
  accO[0][14] = MF16(af0, q2, accO[0][14]); accO[1][14] = MF16(af1, q2, accO[1][14]); \
  accO[0][15] = MF16(af0, q3, accO[0][15]); accO[1][15] = MF16(af1, q3, accO[1][15]); \
}

// stage one chunk-pair (65792 B) with 512 threads: 8 x 16B rounds + 256B tail
#define STAGE(GSRC, LDST) { \
  _Pragma("unroll") for (int j_ = 0; j_ < 8; ++j_) { \
    const int off_ = (j_ << 13) + (tid << 4); \
    __builtin_amdgcn_global_load_lds((const GAS u32*)((GSRC) + off_), \
                                     (LAS u32*)((LDST) + off_), 16, 0, 0); \
  } \
  if (tid < 16) { \
    const int off_ = 65536 + (tid << 4); \
    __builtin_amdgcn_global_load_lds((const GAS u32*)((GSRC) + off_), \
                                     (LAS u32*)((LDST) + off_), 16, 0, 0); \
  } \
}

// ---------------- fused FFN: M=32/wave @ (512,2); 16x16x32 tiling =
// 4 indep GEMM1 chains + 32 indep GEMM2 MFMAs; weight reads shared by
// both 16-token halves. Staging/barriers identical to r10. ----------------
__global__ __launch_bounds__(512, 2) void k_ffn(
    const float* __restrict__ x, const float* __restrict__ As,
    const float* __restrict__ Bs, const float* __restrict__ b2,
    const bf16_t* __restrict__ wsW, float* __restrict__ out) {
  __shared__ __attribute__((aligned(128))) unsigned char lds[2 * PAIRB];  // 128.5KB

  const int tid = threadIdx.x;            // 0..511, 8 waves
  const int lane = tid & 63;
  const int w = tid >> 6;
  const int G4 = lane >> 4;               // 0..3
  const int c15 = lane & 15;
  const int lane16 = lane << 4;

  const int tok0 = blockIdx.x << 8;       // 256 tokens / block
  const int b = blockIdx.x >> 3;          // 8 blocks per batch row
  const int t0 = tok0 + (w << 5);         // this wave's 32 tokens (2 halves of 16)

  const char* wsb = (const char*)wsW;
  const f32x4 Z4 = {0.f, 0.f, 0.f, 0.f};

  // stage pair 0 into buffer 0
  STAGE(wsb, &lds[0]);

  // prologue: normalized h fragments. hfrag[th][ks]: lane holds
  // h[t0+16*th+c15][ks*32 + 8*G4 + e], e=0..7.   (64 VGPR)
  bf16x8 hfrag[2][8];
  {
    const float* ar = As + b * C_N;
    const float* br = Bs + b * C_N;
#pragma unroll
    for (int ks = 0; ks < 8; ++ks) {
      const int c0 = (ks << 5) + (G4 << 3);
      const f32x8 av = *(const f32x8*)(ar + c0);
      const f32x8 bv = *(const f32x8*)(br + c0);
#pragma unroll
      for (int th = 0; th < 2; ++th) {
        const float* xrow = x + (size_t)(t0 + (th << 4) + c15) * C_N;
        f32x8 xv = *(const f32x8*)(xrow + c0);
        f32x8 hv = xv * av + bv;
#pragma unroll
        for (int e = 0; e < 8; ++e) hfrag[th][ks][e] = (bf16_t)hv[e];
      }
    }
  }

  f32x4 accO[2][16];
#pragma unroll
  for (int th = 0; th < 2; ++th)
#pragma unroll
    for (int ct = 0; ct < 16; ++ct) accO[th][ct] = Z4;

  __syncthreads();   // pair 0 staged

#pragma unroll 1
  for (int it = 0; it < NITER; ++it) {
    const unsigned char* buf = &lds[(it & 1) * PAIRB];

    if (it + 1 < NITER) {
      const char* gsrc = wsb + (size_t)(it + 1) * PAIRB;
      unsigned char* ldst = &lds[((it + 1) & 1) * PAIRB];
      STAGE(gsrc, ldst);
    }

    CHUNK(buf);          // chunk 2it
    CHUNK(buf + CHB);    // chunk 2it+1

    if (it + 1 < NITER) __syncthreads();
  }

  // epilogue: out = accO + b2 + x
  // token = t0 + th*16 + 4*G4 + r, col = ct*16 + c15
#pragma unroll
  for (int th = 0; th < 2; ++th) {
    const int tbase = t0 + (th << 4) + (G4 << 2);
    const float* xbase = x + (size_t)tbase * C_N;
    float* obase = out + (size_t)tbase * C_N;
#pragma unroll
    for (int ct = 0; ct < 16; ++ct) {
      const int c = (ct << 4) + c15;
      const float b2v = b2[c];
#pragma unroll
      for (int r = 0; r < 4; ++r) {
        const size_t idx = (size_t)r * C_N + c;
        obase[idx] = accO[th][ct][r] + b2v + xbase[idx];
      }
    }
  }
}

extern "C" void kernel_launch(void* const* d_in, const int* in_sizes, int n_in,
                              void* d_out, int out_size, void* d_ws, size_t ws_size,
                              hipStream_t stream) {
  const float* x     = (const float*)d_in[0];
  const float* gamma = (const float*)d_in[1];
  const float* beta  = (const float*)d_in[2];
  const float* W1    = (const float*)d_in[3];
  const float* b1    = (const float*)d_in[4];
  const float* W2    = (const float*)d_in[5];
  const float* b2    = (const float*)d_in[6];
  float* out = (float*)d_out;

  char* ws = (char*)d_ws;
  bf16_t* wsW  = (bf16_t*)ws;                           // 32 x 32896 = 1.004 MB
  float* psum  = (float*)(ws + (1088 << 10));           // 512 KB
  float* psq   = (float*)(ws + (1600 << 10));           // 512 KB
  float* As    = (float*)(ws + (2112 << 10));           // 32 KB
  float* Bs    = (float*)(ws + (2112 << 10) + (32 << 10));

  k_prep<<<257, 256, 0, stream>>>(W1, b1, W2, wsW);
  k_stats_partial<<<B_N * NSPLIT, 256, 0, stream>>>(x, psum, psq);
  k_stats_final<<<B_N, 256, 0, stream>>>(psum, psq, gamma, beta, As, Bs);
  k_ffn<<<256, 512, 0, stream>>>(x, As, Bs, b2, wsW, out);
}

// Round 13
// 97.928 us; speedup vs baseline: 1.0920x; 1.0203x over previous
//
#include <hip/hip_runtime.h>
#include <hip/hip_bf16.h>

typedef __bf16 bf16_t;
typedef __bf16 bf16x8 __attribute__((ext_vector_type(8)));
typedef float f32x4 __attribute__((ext_vector_type(4)));
typedef float f32x8 __attribute__((ext_vector_type(8)));
typedef unsigned int u32;

#define GAS __attribute__((address_space(1)))
#define LAS __attribute__((address_space(3)))

#define B_N 32
#define T_N 2048
#define C_N 256
#define F_N 1024
#define NSPLIT 16
#define TSUB 128
#define NCHUNK 32
#define CHB 32896               // 16KB W1 + 16KB W2 + 128B bias

#define MF16(A, B, C) __builtin_amdgcn_mfma_f32_16x16x32_bf16((A), (B), (C), 0, 0, 0)

// ---------------- weight prep: per-chunk images {W1 | W2 | bias} ----------------
// 16x16x32 fragment layouts (HW-verified): A/B k=(l>>4)*8+e, C/D row=(l>>4)*4+r col=l&15.
// W1 entry (ks 0..7, ht 0..1, G 0..3, c 0..15) 16B at ks*2048+ht*1024+G*256+c*16:
//   { bf16(W1[ks*32+8G+e][ch*32+ht*16+c]) e=0..7 }
// W2 entry (ct 0..15, G, c) 16B at 16384+ct*1024+G*256+c*16:
//   { bf16(W2[ch*32 + 4G+(e&3)+16*(e>>2)][ct*16+c]) }   (perm matches D1 reg order)
// bias (ht, G) f32x4 at 32768+ht*64+G*16 = b1[ch*32+ht*16+4G .. +3]
__global__ __launch_bounds__(256) void k_prep(
    const float* __restrict__ W1, const float* __restrict__ b1,
    const float* __restrict__ W2, bf16_t* __restrict__ wsW) {
  const int id = blockIdx.x * 256 + threadIdx.x;      // 0 .. 65791
  const int ch = id / 2056;
  const int r = id % 2056;
  char* base = (char*)wsW + (size_t)ch * CHB;
  if (r < 1024) {
    const int ks = r >> 7, rem = r & 127;
    const int ht = rem >> 6, rem2 = rem & 63;
    const int G = rem2 >> 4, c = rem2 & 15;
    const int h = (ch << 5) + (ht << 4) + c;
    bf16x8 v;
#pragma unroll
    for (int e = 0; e < 8; ++e)
      v[e] = (bf16_t)W1[(size_t)((ks << 5) + (G << 3) + e) * F_N + h];
    *(bf16x8*)(base + (ks << 11) + (ht << 10) + (G << 8) + (c << 4)) = v;
  } else if (r < 2048) {
    const int t = r - 1024;
    const int ct = t >> 6, rem = t & 63;
    const int G = rem >> 4, c = rem & 15;
    bf16x8 v;
#pragma unroll
    for (int e = 0; e < 8; ++e) {
      const int hid = (ch << 5) + (G << 2) + (e & 3) + ((e >> 2) << 4);
      v[e] = (bf16_t)W2[(size_t)hid * C_N + (ct << 4) + c];
    }
    *(bf16x8*)(base + 16384 + (ct << 10) + (G << 8) + (c << 4)) = v;
  } else {
    const int t = r - 2048;       // 0..7
    const int ht = t >> 2, G = t & 3;
    f32x4 v;
#pragma unroll
    for (int j = 0; j < 4; ++j)
      v[j] = b1[(ch << 5) + (ht << 4) + (G << 2) + j];
    *(f32x4*)(base + 32768 + (ht << 6) + (G << 4)) = v;
  }
}

// ---------------- stats pass 1: partial sum / sumsq over a T-slice ----------------
__global__ __launch_bounds__(256) void k_stats_partial(
    const float* __restrict__ x, float* __restrict__ psum, float* __restrict__ psq) {
  const int blk = blockIdx.x;
  const int b = blk / NSPLIT, s = blk % NSPLIT;
  const int tid = threadIdx.x;
  const int c4 = (tid & 63) << 2;
  const int tg = tid >> 6;
  const float* xb = x + ((size_t)b * T_N + (size_t)s * TSUB) * C_N;
  f32x4 sum = {0.f, 0.f, 0.f, 0.f};
  f32x4 sq  = {0.f, 0.f, 0.f, 0.f};
#pragma unroll 4
  for (int i = 0; i < TSUB / 4; ++i) {
    const int t = tg + (i << 2);
    f32x4 v = *(const f32x4*)(xb + (size_t)t * C_N + c4);
    sum += v;
    sq += v * v;
  }
  __shared__ f32x4 ls[256];
  __shared__ f32x4 lq[256];
  ls[tid] = sum; lq[tid] = sq;
  __syncthreads();
  if (tid < 64) {
    f32x4 S = ls[tid] + ls[tid + 64] + ls[tid + 128] + ls[tid + 192];
    f32x4 Q = lq[tid] + lq[tid + 64] + lq[tid + 128] + lq[tid + 192];
    *(f32x4*)(psum + (size_t)blk * C_N + c4) = S;
    *(f32x4*)(psq  + (size_t)blk * C_N + c4) = Q;
  }
}

// ---------------- stats pass 2: fused scale/shift (ddof=1) ----------------
__global__ __launch_bounds__(256) void k_stats_final(
    const float* __restrict__ psum, const float* __restrict__ psq,
    const float* __restrict__ gamma, const float* __restrict__ beta,
    float* __restrict__ As, float* __restrict__ Bs) {
  const int b = blockIdx.x, c = threadIdx.x;
  float S = 0.f, Q = 0.f;
#pragma unroll
  for (int s = 0; s < NSPLIT; ++s) {
    S += psum[(size_t)(b * NSPLIT + s) * C_N + c];
    Q += psq[(size_t)(b * NSPLIT + s) * C_N + c];
  }
  const float mu = S / (float)T_N;
  const float var = (Q - (float)T_N * mu * mu) / (float)(T_N - 1);
  const float a = rsqrtf(var + 1e-5f) * gamma[c];
  As[b * C_N + c] = a;
  Bs[b * C_N + c] = beta[c] - mu * a;
}

// one full chunk: GEMM1 (bias as C-init, 4 chains of 8) -> ReLU pack -> GEMM2 (32 indep)
#define R1(off) (*(const bf16x8*)(w1_ + (off)))
#define R2(off) (*(const bf16x8*)(w2_ + (off)))
#define CHUNK(CB) { \
  const unsigned char* w1_ = (CB) + lane16; \
  const unsigned char* w2_ = (CB) + 16384 + lane16; \
  const f32x4 bq0 = *(const f32x4*)((CB) + 32768 + (G4 << 4)); \
  const f32x4 bq1 = *(const f32x4*)((CB) + 32768 + 64 + (G4 << 4)); \
  bf16x8 p0 = R1(0), p1 = R1(1024), p2 = R1(2048), p3 = R1(3072); \
  f32x4 D00 = bq0, D01 = bq0, D10 = bq1, D11 = bq1; \
  D00 = MF16(p0, hfrag[0][0], D00); D01 = MF16(p0, hfrag[1][0], D01); p0 = R1(4096); \
  D10 = MF16(p1, hfrag[0][0], D10); D11 = MF16(p1, hfrag[1][0], D11); p1 = R1(5120); \
  D00 = MF16(p2, hfrag[0][1], D00); D01 = MF16(p2, hfrag[1][1], D01); p2 = R1(6144); \
  D10 = MF16(p3, hfrag[0][1], D10); D11 = MF16(p3, hfrag[1][1], D11); p3 = R1(7168); \
  D00 = MF16(p0, hfrag[0][2], D00); D01 = MF16(p0, hfrag[1][2], D01); p0 = R1(8192); \
  D10 = MF16(p1, hfrag[0][2], D10); D11 = MF16(p1, hfrag[1][2], D11); p1 = R1(9216); \
  D00 = MF16(p2, hfrag[0][3], D00); D01 = MF16(p2, hfrag[1][3], D01); p2 = R1(10240); \
  D10 = MF16(p3, hfrag[0][3], D10); D11 = MF16(p3, hfrag[1][3], D11); p3 = R1(11264); \
  D00 = MF16(p0, hfrag[0][4], D00); D01 = MF16(p0, hfrag[1][4], D01); p0 = R1(12288); \
  D10 = MF16(p1, hfrag[0][4], D10); D11 = MF16(p1, hfrag[1][4], D11); p1 = R1(13312); \
  D00 = MF16(p2, hfrag[0][5], D00); D01 = MF16(p2, hfrag[1][5], D01); p2 = R1(14336); \
  D10 = MF16(p3, hfrag[0][5], D10); D11 = MF16(p3, hfrag[1][5], D11); p3 = R1(15360); \
  D00 = MF16(p0, hfrag[0][6], D00); D01 = MF16(p0, hfrag[1][6], D01); \
  D10 = MF16(p1, hfrag[0][6], D10); D11 = MF16(p1, hfrag[1][6], D11); \
  D00 = MF16(p2, hfrag[0][7], D00); D01 = MF16(p2, hfrag[1][7], D01); \
  D10 = MF16(p3, hfrag[0][7], D10); D11 = MF16(p3, hfrag[1][7], D11); \
  bf16x8 af0, af1; \
  _Pragma("unroll") for (int e_ = 0; e_ < 8; ++e_) { \
    const int r_ = e_ & 3; \
    float v0 = (e_ < 4 ? D00[r_] : D10[r_]); \
    float v1 = (e_ < 4 ? D01[r_] : D11[r_]); \
    v0 = v0 > 0.f ? v0 : 0.f; \
    v1 = v1 > 0.f ? v1 : 0.f; \
    af0[e_] = (bf16_t)v0; af1[e_] = (bf16_t)v1; \
  } \
  bf16x8 q0 = R2(0), q1 = R2(1024), q2 = R2(2048), q3 = R2(3072); \
  accO[0][0]  = MF16(af0, q0, accO[0][0]);  accO[1][0]  = MF16(af1, q0, accO[1][0]);  q0 = R2(4096); \
  accO[0][1]  = MF16(af0, q1, accO[0][1]);  accO[1][1]  = MF16(af1, q1, accO[1][1]);  q1 = R2(5120); \
  accO[0][2]  = MF16(af0, q2, accO[0][2]);  accO[1][2]  = MF16(af1, q2, accO[1][2]);  q2 = R2(6144); \
  accO[0][3]  = MF16(af0, q3, accO[0][3]);  accO[1][3]  = MF16(af1, q3, accO[1][3]);  q3 = R2(7168); \
  accO[0][4]  = MF16(af0, q0, accO[0][4]);  accO[1][4]  = MF16(af1, q0, accO[1][4]);  q0 = R2(8192); \
  accO[0][5]  = MF16(af0, q1, accO[0][5]);  accO[1][5]  = MF16(af1, q1, accO[1][5]);  q1 = R2(9216); \
  accO[0][6]  = MF16(af0, q2, accO[0][6]);  accO[1][6]  = MF16(af1, q2, accO[1][6]);  q2 = R2(10240); \
  accO[0][7]  = MF16(af0, q3, accO[0][7]);  accO[1][7]  = MF16(af1, q3, accO[1][7]);  q3 = R2(11264); \
  accO[0][8]  = MF16(af0, q0, accO[0][8]);  accO[1][8]  = MF16(af1, q0, accO[1][8]);  q0 = R2(12288); \
  accO[0][9]  = MF16(af0, q1, accO[0][9]);  accO[1][9]  = MF16(af1, q1, accO[1][9]);  q1 = R2(13312); \
  accO[0][10] = MF16(af0, q2, accO[0][10]); accO[1][10] = MF16(af1, q2, accO[1][10]); q2 = R2(14336); \
  accO[0][11] = MF16(af0, q3, accO[0][11]); accO[1][11] = MF16(af1, q3, accO[1][11]); q3 = R2(15360); \
  accO[0][12] = MF16(af0, q0, accO[0][12]); accO[1][12] = MF16(af1, q0, accO[1][12]); \
  accO[0][13] = MF16(af0, q1, accO[0][13]); accO[1][13] = MF16(af1, q1, accO[1][13]); \
  accO[0][14] = MF16(af0, q2, accO[0][14]); accO[1][14] = MF16(af1, q2, accO[1][14]); \
  accO[0][15] = MF16(af0, q3, accO[0][15]); accO[1][15] = MF16(af1, q3, accO[1][15]); \
}

// stage one chunk (32896 B) with 256 threads: 8 x 16B rounds + 128B tail
#define STAGE(GSRC, LDST) { \
  _Pragma("unroll") for (int j_ = 0; j_ < 8; ++j_) { \
    const int off_ = (j_ << 12) + (tid << 4); \
    __builtin_amdgcn_global_load_lds((const GAS u32*)((GSRC) + off_), \
                                     (LAS u32*)((LDST) + off_), 16, 0, 0); \
  } \
  if (tid < 8) { \
    const int off_ = 32768 + (tid << 4); \
    __builtin_amdgcn_global_load_lds((const GAS u32*)((GSRC) + off_), \
                                     (LAS u32*)((LDST) + off_), 16, 0, 0); \
  } \
}

// ---------------- fused FFN: M=32/wave; 4-wave blocks, 2 independent blocks/CU
// (phase diversity, small barrier scope); bias as MFMA C-init (no bias VALU);
// 16x16x32 tiling, weight reads shared by both 16-token halves. ----------------
__global__ __launch_bounds__(256, 2) void k_ffn(
    const float* __restrict__ x, const float* __restrict__ As,
    const float* __restrict__ Bs, const float* __restrict__ b2,
    const bf16_t* __restrict__ wsW, float* __restrict__ out) {
  __shared__ __attribute__((aligned(128))) unsigned char lds[2 * CHB];  // 64.25KB

  const int tid = threadIdx.x;            // 0..255, 4 waves
  const int lane = tid & 63;
  const int w = tid >> 6;
  const int G4 = lane >> 4;               // 0..3
  const int c15 = lane & 15;
  const int lane16 = lane << 4;

  const int tok0 = blockIdx.x << 7;       // 128 tokens / block
  const int b = blockIdx.x >> 4;          // 16 blocks per batch row
  const int t0 = tok0 + (w << 5);         // this wave's 32 tokens (2 halves of 16)

  const char* wsb = (const char*)wsW;
  const f32x4 Z4 = {0.f, 0.f, 0.f, 0.f};

  // stage chunk 0 into buffer 0
  STAGE(wsb, &lds[0]);

  // prologue: normalized h fragments. hfrag[th][ks]: lane holds
  // h[t0+16*th+c15][ks*32 + 8*G4 + e], e=0..7.   (64 VGPR)
  bf16x8 hfrag[2][8];
  {
    const float* ar = As + b * C_N;
    const float* br = Bs + b * C_N;
#pragma unroll
    for (int ks = 0; ks < 8; ++ks) {
      const int c0 = (ks << 5) + (G4 << 3);
      const f32x8 av = *(const f32x8*)(ar + c0);
      const f32x8 bv = *(const f32x8*)(br + c0);
#pragma unroll
      for (int th = 0; th < 2; ++th) {
        const float* xrow = x + (size_t)(t0 + (th << 4) + c15) * C_N;
        f32x8 xv = *(const f32x8*)(xrow + c0);
        f32x8 hv = xv * av + bv;
#pragma unroll
        for (int e = 0; e < 8; ++e) hfrag[th][ks][e] = (bf16_t)hv[e];
      }
    }
  }

  f32x4 accO[2][16];
#pragma unroll
  for (int th = 0; th < 2; ++th)
#pragma unroll
    for (int ct = 0; ct < 16; ++ct) accO[th][ct] = Z4;

  __syncthreads();   // chunk 0 staged

#pragma unroll 1
  for (int ch = 0; ch < NCHUNK; ++ch) {
    const unsigned char* buf = &lds[(ch & 1) * CHB];

    if (ch + 1 < NCHUNK) {
      const char* gsrc = wsb + (size_t)(ch + 1) * CHB;
      unsigned char* ldst = &lds[((ch + 1) & 1) * CHB];
      STAGE(gsrc, ldst);
    }

    CHUNK(buf);

    if (ch + 1 < NCHUNK) __syncthreads();
  }

  // epilogue: out = accO + b2 + x
  // token = t0 + th*16 + 4*G4 + r, col = ct*16 + c15
#pragma unroll
  for (int th = 0; th < 2; ++th) {
    const int tbase = t0 + (th << 4) + (G4 << 2);
    const float* xbase = x + (size_t)tbase * C_N;
    float* obase = out + (size_t)tbase * C_N;
#pragma unroll
    for (int ct = 0; ct < 16; ++ct) {
      const int c = (ct << 4) + c15;
      const float b2v = b2[c];
#pragma unroll
      for (int r = 0; r < 4; ++r) {
        const size_t idx = (size_t)r * C_N + c;
        obase[idx] = accO[th][ct][r] + b2v + xbase[idx];
      }
    }
  }
}

extern "C" void kernel_launch(void* const* d_in, const int* in_sizes, int n_in,
                              void* d_out, int out_size, void* d_ws, size_t ws_size,
                              hipStream_t stream) {
  const float* x     = (const float*)d_in[0];
  const float* gamma = (const float*)d_in[1];
  const float* beta  = (const float*)d_in[2];
  const float* W1    = (const float*)d_in[3];
  const float* b1    = (const float*)d_in[4];
  const float* W2    = (const float*)d_in[5];
  const float* b2    = (const float*)d_in[6];
  float* out = (float*)d_out;

  char* ws = (char*)d_ws;
  bf16_t* wsW  = (bf16_t*)ws;                           // 32 x 32896 = 1.004 MB
  float* psum  = (float*)(ws + (1088 << 10));           // 512 KB
  float* psq   = (float*)(ws + (1600 << 10));           // 512 KB
  float* As    = (float*)(ws + (2112 << 10));           // 32 KB
  float* Bs    = (float*)(ws + (2112 << 10) + (32 << 10));

  k_prep<<<257, 256, 0, stream>>>(W1, b1, W2, wsW);
  k_stats_partial<<<B_N * NSPLIT, 256, 0, stream>>>(x, psum, psq);
  k_stats_final<<<B_N, 256, 0, stream>>>(psum, psq, gamma, beta, As, Bs);
  k_ffn<<<512, 256, 0, stream>>>(x, As, Bs, b2, wsW, out);
}

// Round 14
// 93.121 us; speedup vs baseline: 1.1484x; 1.0516x over previous
//
#include <hip/hip_runtime.h>
#include <hip/hip_bf16.h>

typedef __bf16 bf16_t;
typedef __bf16 bf16x8 __attribute__((ext_vector_type(8)));
typedef float f32x4 __attribute__((ext_vector_type(4)));
typedef float f32x8 __attribute__((ext_vector_type(8)));
typedef unsigned int u32;

#define GAS __attribute__((address_space(1)))
#define LAS __attribute__((address_space(3)))

#define B_N 32
#define T_N 2048
#define C_N 256
#define F_N 1024
#define NSPLIT 16
#define TSUB 128
#define NCHUNK 32
#define CHB 32896               // 16KB W1 + 16KB W2 + 128B bias

#define MF16(A, B, C) __builtin_amdgcn_mfma_f32_16x16x32_bf16((A), (B), (C), 0, 0, 0)

// ---------------- fused pre-pass: weight prep (gather-bound) + stats pass 1
// (stream-bound) in one kernel so the two overlap on the device. ----------------
// Blocks [0,512): per-slice partial sum/sumsq of x.
// Blocks [512,769): build per-chunk weight images {W1 | W2 | bias} in ws.
//   16x16x32 fragment layouts (HW-verified): A/B k=(l>>4)*8+e, C/D row=(l>>4)*4+r col=l&15.
//   W1 entry (ks,ht,G,c) 16B at ks*2048+ht*1024+G*256+c*16 = {bf16(W1[ks*32+8G+e][ch*32+ht*16+c])}
//   W2 entry (ct,G,c) 16B at 16384+ct*1024+G*256+c*16 = {bf16(W2[ch*32+4G+(e&3)+16*(e>>2)][ct*16+c])}
//   bias (ht,G) f32x4 at 32768+ht*64+G*16
__global__ __launch_bounds__(256) void k_pre(
    const float* __restrict__ x, const float* __restrict__ W1,
    const float* __restrict__ b1, const float* __restrict__ W2,
    float* __restrict__ psum, float* __restrict__ psq, bf16_t* __restrict__ wsW) {
  const int tid = threadIdx.x;
  if (blockIdx.x < 512) {
    const int blk = blockIdx.x;
    const int b = blk / NSPLIT, s = blk % NSPLIT;
    const int c4 = (tid & 63) << 2;
    const int tg = tid >> 6;
    const float* xb = x + ((size_t)b * T_N + (size_t)s * TSUB) * C_N;
    f32x4 sum = {0.f, 0.f, 0.f, 0.f};
    f32x4 sq  = {0.f, 0.f, 0.f, 0.f};
#pragma unroll 4
    for (int i = 0; i < TSUB / 4; ++i) {
      const int t = tg + (i << 2);
      f32x4 v = *(const f32x4*)(xb + (size_t)t * C_N + c4);
      sum += v;
      sq += v * v;
    }
    __shared__ f32x4 ls[256];
    __shared__ f32x4 lq[256];
    ls[tid] = sum; lq[tid] = sq;
    __syncthreads();
    if (tid < 64) {
      f32x4 S = ls[tid] + ls[tid + 64] + ls[tid + 128] + ls[tid + 192];
      f32x4 Q = lq[tid] + lq[tid + 64] + lq[tid + 128] + lq[tid + 192];
      *(f32x4*)(psum + (size_t)blk * C_N + c4) = S;
      *(f32x4*)(psq  + (size_t)blk * C_N + c4) = Q;
    }
  } else {
    const int id = (blockIdx.x - 512) * 256 + tid;    // 0 .. 65791
    const int ch = id / 2056;
    const int r = id % 2056;
    char* base = (char*)wsW + (size_t)ch * CHB;
    if (r < 1024) {
      const int ks = r >> 7, rem = r & 127;
      const int ht = rem >> 6, rem2 = rem & 63;
      const int G = rem2 >> 4, c = rem2 & 15;
      const int h = (ch << 5) + (ht << 4) + c;
      bf16x8 v;
#pragma unroll
      for (int e = 0; e < 8; ++e)
        v[e] = (bf16_t)W1[(size_t)((ks << 5) + (G << 3) + e) * F_N + h];
      *(bf16x8*)(base + (ks << 11) + (ht << 10) + (G << 8) + (c << 4)) = v;
    } else if (r < 2048) {
      const int t = r - 1024;
      const int ct = t >> 6, rem = t & 63;
      const int G = rem >> 4, c = rem & 15;
      bf16x8 v;
#pragma unroll
      for (int e = 0; e < 8; ++e) {
        const int hid = (ch << 5) + (G << 2) + (e & 3) + ((e >> 2) << 4);
        v[e] = (bf16_t)W2[(size_t)hid * C_N + (ct << 4) + c];
      }
      *(bf16x8*)(base + 16384 + (ct << 10) + (G << 8) + (c << 4)) = v;
    } else {
      const int t = r - 2048;       // 0..7
      const int ht = t >> 2, G = t & 3;
      f32x4 v;
#pragma unroll
      for (int j = 0; j < 4; ++j)
        v[j] = b1[(ch << 5) + (ht << 4) + (G << 2) + j];
      *(f32x4*)(base + 32768 + (ht << 6) + (G << 4)) = v;
    }
  }
}

// ---------------- stats pass 2: fused scale/shift (ddof=1) ----------------
__global__ __launch_bounds__(256) void k_stats_final(
    const float* __restrict__ psum, const float* __restrict__ psq,
    const float* __restrict__ gamma, const float* __restrict__ beta,
    float* __restrict__ As, float* __restrict__ Bs) {
  const int b = blockIdx.x, c = threadIdx.x;
  float S = 0.f, Q = 0.f;
#pragma unroll
  for (int s = 0; s < NSPLIT; ++s) {
    S += psum[(size_t)(b * NSPLIT + s) * C_N + c];
    Q += psq[(size_t)(b * NSPLIT + s) * C_N + c];
  }
  const float mu = S / (float)T_N;
  const float var = (Q - (float)T_N * mu * mu) / (float)(T_N - 1);
  const float a = rsqrtf(var + 1e-5f) * gamma[c];
  As[b * C_N + c] = a;
  Bs[b * C_N + c] = beta[c] - mu * a;
}

// one full chunk: GEMM1 (bias as C-init, 4 chains of 8) -> ReLU pack -> GEMM2 (32 indep).
// q0/q1 hoisted into GEMM1's tail so GEMM2's first MFMAs see warm reads.
#define R1(off) (*(const bf16x8*)(w1_ + (off)))
#define R2(off) (*(const bf16x8*)(w2_ + (off)))
#define CHUNK(CB) { \
  const unsigned char* w1_ = (CB) + lane16; \
  const unsigned char* w2_ = (CB) + 16384 + lane16; \
  const f32x4 bq0 = *(const f32x4*)((CB) + 32768 + (G4 << 4)); \
  const f32x4 bq1 = *(const f32x4*)((CB) + 32768 + 64 + (G4 << 4)); \
  bf16x8 p0 = R1(0), p1 = R1(1024), p2 = R1(2048), p3 = R1(3072); \
  f32x4 D00 = bq0, D01 = bq0, D10 = bq1, D11 = bq1; \
  D00 = MF16(p0, hfrag[0][0], D00); D01 = MF16(p0, hfrag[1][0], D01); p0 = R1(4096); \
  D10 = MF16(p1, hfrag[0][0], D10); D11 = MF16(p1, hfrag[1][0], D11); p1 = R1(5120); \
  D00 = MF16(p2, hfrag[0][1], D00); D01 = MF16(p2, hfrag[1][1], D01); p2 = R1(6144); \
  D10 = MF16(p3, hfrag[0][1], D10); D11 = MF16(p3, hfrag[1][1], D11); p3 = R1(7168); \
  D00 = MF16(p0, hfrag[0][2], D00); D01 = MF16(p0, hfrag[1][2], D01); p0 = R1(8192); \
  D10 = MF16(p1, hfrag[0][2], D10); D11 = MF16(p1, hfrag[1][2], D11); p1 = R1(9216); \
  D00 = MF16(p2, hfrag[0][3], D00); D01 = MF16(p2, hfrag[1][3], D01); p2 = R1(10240); \
  D10 = MF16(p3, hfrag[0][3], D10); D11 = MF16(p3, hfrag[1][3], D11); p3 = R1(11264); \
  D00 = MF16(p0, hfrag[0][4], D00); D01 = MF16(p0, hfrag[1][4], D01); p0 = R1(12288); \
  D10 = MF16(p1, hfrag[0][4], D10); D11 = MF16(p1, hfrag[1][4], D11); p1 = R1(13312); \
  D00 = MF16(p2, hfrag[0][5], D00); D01 = MF16(p2, hfrag[1][5], D01); p2 = R1(14336); \
  D10 = MF16(p3, hfrag[0][5], D10); D11 = MF16(p3, hfrag[1][5], D11); p3 = R1(15360); \
  D00 = MF16(p0, hfrag[0][6], D00); D01 = MF16(p0, hfrag[1][6], D01); \
  D10 = MF16(p1, hfrag[0][6], D10); D11 = MF16(p1, hfrag[1][6], D11); \
  bf16x8 q0 = R2(0), q1 = R2(1024); \
  D00 = MF16(p2, hfrag[0][7], D00); D01 = MF16(p2, hfrag[1][7], D01); \
  D10 = MF16(p3, hfrag[0][7], D10); D11 = MF16(p3, hfrag[1][7], D11); \
  bf16x8 af0, af1; \
  _Pragma("unroll") for (int e_ = 0; e_ < 8; ++e_) { \
    const int r_ = e_ & 3; \
    float v0 = (e_ < 4 ? D00[r_] : D10[r_]); \
    float v1 = (e_ < 4 ? D01[r_] : D11[r_]); \
    v0 = v0 > 0.f ? v0 : 0.f; \
    v1 = v1 > 0.f ? v1 : 0.f; \
    af0[e_] = (bf16_t)v0; af1[e_] = (bf16_t)v1; \
  } \
  bf16x8 q2 = R2(2048), q3 = R2(3072); \
  accO[0][0]  = MF16(af0, q0, accO[0][0]);  accO[1][0]  = MF16(af1, q0, accO[1][0]);  q0 = R2(4096); \
  accO[0][1]  = MF16(af0, q1, accO[0][1]);  accO[1][1]  = MF16(af1, q1, accO[1][1]);  q1 = R2(5120); \
  accO[0][2]  = MF16(af0, q2, accO[0][2]);  accO[1][2]  = MF16(af1, q2, accO[1][2]);  q2 = R2(6144); \
  accO[0][3]  = MF16(af0, q3, accO[0][3]);  accO[1][3]  = MF16(af1, q3, accO[1][3]);  q3 = R2(7168); \
  accO[0][4]  = MF16(af0, q0, accO[0][4]);  accO[1][4]  = MF16(af1, q0, accO[1][4]);  q0 = R2(8192); \
  accO[0][5]  = MF16(af0, q1, accO[0][5]);  accO[1][5]  = MF16(af1, q1, accO[1][5]);  q1 = R2(9216); \
  accO[0][6]  = MF16(af0, q2, accO[0][6]);  accO[1][6]  = MF16(af1, q2, accO[1][6]);  q2 = R2(10240); \
  accO[0][7]  = MF16(af0, q3, accO[0][7]);  accO[1][7]  = MF16(af1, q3, accO[1][7]);  q3 = R2(11264); \
  accO[0][8]  = MF16(af0, q0, accO[0][8]);  accO[1][8]  = MF16(af1, q0, accO[1][8]);  q0 = R2(12288); \
  accO[0][9]  = MF16(af0, q1, accO[0][9]);  accO[1][9]  = MF16(af1, q1, accO[1][9]);  q1 = R2(13312); \
  accO[0][10] = MF16(af0, q2, accO[0][10]); accO[1][10] = MF16(af1, q2, accO[1][10]); q2 = R2(14336); \
  accO[0][11] = MF16(af0, q3, accO[0][11]); accO[1][11] = MF16(af1, q3, accO[1][11]); q3 = R2(15360); \
  accO[0][12] = MF16(af0, q0, accO[0][12]); accO[1][12] = MF16(af1, q0, accO[1][12]); \
  accO[0][13] = MF16(af0, q1, accO[0][13]); accO[1][13] = MF16(af1, q1, accO[1][13]); \
  accO[0][14] = MF16(af0, q2, accO[0][14]); accO[1][14] = MF16(af1, q2, accO[1][14]); \
  accO[0][15] = MF16(af0, q3, accO[0][15]); accO[1][15] = MF16(af1, q3, accO[1][15]); \
}

// stage one chunk (32896 B) with 256 threads: 8 x 16B rounds + 128B tail
#define STAGE(GSRC, LDST) { \
  _Pragma("unroll") for (int j_ = 0; j_ < 8; ++j_) { \
    const int off_ = (j_ << 12) + (tid << 4); \
    __builtin_amdgcn_global_load_lds((const GAS u32*)((GSRC) + off_), \
                                     (LAS u32*)((LDST) + off_), 16, 0, 0); \
  } \
  if (tid < 8) { \
    const int off_ = 32768 + (tid << 4); \
    __builtin_amdgcn_global_load_lds((const GAS u32*)((GSRC) + off_), \
                                     (LAS u32*)((LDST) + off_), 16, 0, 0); \
  } \
}

// ---------------- fused FFN: M=32/wave; 4-wave blocks, 2 independent blocks/CU;
// bias as MFMA C-init; 16x16x32 tiling, weight reads shared by both 16-token halves. ----------------
__global__ __launch_bounds__(256, 2) void k_ffn(
    const float* __restrict__ x, const float* __restrict__ As,
    const float* __restrict__ Bs, const float* __restrict__ b2,
    const bf16_t* __restrict__ wsW, float* __restrict__ out) {
  __shared__ __attribute__((aligned(128))) unsigned char lds[2 * CHB];  // 64.25KB

  const int tid = threadIdx.x;            // 0..255, 4 waves
  const int lane = tid & 63;
  const int w = tid >> 6;
  const int G4 = lane >> 4;               // 0..3
  const int c15 = lane & 15;
  const int lane16 = lane << 4;

  const int tok0 = blockIdx.x << 7;       // 128 tokens / block
  const int b = blockIdx.x >> 4;          // 16 blocks per batch row
  const int t0 = tok0 + (w << 5);         // this wave's 32 tokens (2 halves of 16)

  const char* wsb = (const char*)wsW;
  const f32x4 Z4 = {0.f, 0.f, 0.f, 0.f};

  // stage chunk 0 into buffer 0
  STAGE(wsb, &lds[0]);

  // prologue: normalized h fragments. hfrag[th][ks]: lane holds
  // h[t0+16*th+c15][ks*32 + 8*G4 + e], e=0..7.   (64 VGPR)
  bf16x8 hfrag[2][8];
  {
    const float* ar = As + b * C_N;
    const float* br = Bs + b * C_N;
#pragma unroll
    for (int ks = 0; ks < 8; ++ks) {
      const int c0 = (ks << 5) + (G4 << 3);
      const f32x8 av = *(const f32x8*)(ar + c0);
      const f32x8 bv = *(const f32x8*)(br + c0);
#pragma unroll
      for (int th = 0; th < 2; ++th) {
        const float* xrow = x + (size_t)(t0 + (th << 4) + c15) * C_N;
        f32x8 xv = *(const f32x8*)(xrow + c0);
        f32x8 hv = xv * av + bv;
#pragma unroll
        for (int e = 0; e < 8; ++e) hfrag[th][ks][e] = (bf16_t)hv[e];
      }
    }
  }

  f32x4 accO[2][16];
#pragma unroll
  for (int th = 0; th < 2; ++th)
#pragma unroll
    for (int ct = 0; ct < 16; ++ct) accO[th][ct] = Z4;

  __syncthreads();   // chunk 0 staged

#pragma unroll 1
  for (int ch = 0; ch < NCHUNK; ++ch) {
    const unsigned char* buf = &lds[(ch & 1) * CHB];

    if (ch + 1 < NCHUNK) {
      const char* gsrc = wsb + (size_t)(ch + 1) * CHB;
      unsigned char* ldst = &lds[((ch + 1) & 1) * CHB];
      STAGE(gsrc, ldst);
    }

    CHUNK(buf);

    if (ch + 1 < NCHUNK) __syncthreads();
  }

  // epilogue: out = accO + b2 + x
  // token = t0 + th*16 + 4*G4 + r, col = ct*16 + c15
#pragma unroll
  for (int th = 0; th < 2; ++th) {
    const int tbase = t0 + (th << 4) + (G4 << 2);
    const float* xbase = x + (size_t)tbase * C_N;
    float* obase = out + (size_t)tbase * C_N;
#pragma unroll
    for (int ct = 0; ct < 16; ++ct) {
      const int c = (ct << 4) + c15;
      const float b2v = b2[c];
#pragma unroll
      for (int r = 0; r < 4; ++r) {
        const size_t idx = (size_t)r * C_N + c;
        obase[idx] = accO[th][ct][r] + b2v + xbase[idx];
      }
    }
  }
}

extern "C" void kernel_launch(void* const* d_in, const int* in_sizes, int n_in,
                              void* d_out, int out_size, void* d_ws, size_t ws_size,
                              hipStream_t stream) {
  const float* x     = (const float*)d_in[0];
  const float* gamma = (const float*)d_in[1];
  const float* beta  = (const float*)d_in[2];
  const float* W1    = (const float*)d_in[3];
  const float* b1    = (const float*)d_in[4];
  const float* W2    = (const float*)d_in[5];
  const float* b2    = (const float*)d_in[6];
  float* out = (float*)d_out;

  char* ws = (char*)d_ws;
  bf16_t* wsW  = (bf16_t*)ws;                           // 32 x 32896 = 1.004 MB
  float* psum  = (float*)(ws + (1088 << 10));           // 512 KB
  float* psq   = (float*)(ws + (1600 << 10));           // 512 KB
  float* As    = (float*)(ws + (2112 << 10));           // 32 KB
  float* Bs    = (float*)(ws + (2112 << 10) + (32 << 10));

  k_pre<<<769, 256, 0, stream>>>(x, W1, b1, W2, psum, psq, wsW);
  k_stats_final<<<B_N, 256, 0, stream>>>(psum, psq, gamma, beta, As, Bs);
  k_ffn<<<512, 256, 0, stream>>>(x, As, Bs, b2, wsW, out);
}